// Round 9
// baseline (680.419 us; speedup 1.0000x reference)
//
#include <hip/hip_runtime.h>
#include <math.h>

#define EPS_BN 1e-5f
#define NBUK 64
#define BSHIFT 10
#define BCAP 32768

typedef __bf16 bf16x8 __attribute__((ext_vector_type(8)));
typedef float floatx4 __attribute__((ext_vector_type(4)));

__device__ __forceinline__ float lrelu(float x) { return x > 0.f ? x : 0.2f * x; }

// fp32 -> bf16 (RNE) bit pattern
__device__ __forceinline__ unsigned short f2b(float f) {
    unsigned int b = __float_as_uint(f);
    b = (b + 0x7fffu + ((b >> 16) & 1u)) >> 16;
    return (unsigned short)b;
}
// packed ushort2(bf16x2) -> two floats
__device__ __forceinline__ float b2f_lo(unsigned int u) { return __uint_as_float(u << 16); }
__device__ __forceinline__ float b2f_hi(unsigned int u) { return __uint_as_float(u & 0xffff0000u); }

// ---------------- edge dtype probe (parallel) + convert ----------------
__global__ void k_detect64(const int* __restrict__ ei, int* flag, int nwords) {
    int lane = threadIdx.x;  // 64
    int lim = nwords < 512 ? nwords : 512;
    int zeros = 0;
    for (int i = 2 * lane + 1; i < lim; i += 128) zeros += (ei[i] == 0);
    for (int off = 32; off >= 1; off >>= 1) zeros += __shfl_xor(zeros, off, 64);
    if (lane == 0) *flag = (zeros > lim / 8) ? 1 : 0;
}

__global__ void k_convert(const int* __restrict__ ei, const int* __restrict__ flag,
                          int* __restrict__ out, int n) {
    int i0 = (blockIdx.x * blockDim.x + threadIdx.x) * 4;
    int f = *flag;  // uniform
    if (i0 + 4 <= n) {
        int v0, v1, v2, v3;
        if (f) {
            v0 = ei[2 * i0];
            v1 = ei[2 * i0 + 2];
            v2 = ei[2 * i0 + 4];
            v3 = ei[2 * i0 + 6];
        } else {
            int4 v = *(const int4*)(ei + i0);
            v0 = v.x; v1 = v.y; v2 = v.z; v3 = v.w;
        }
        *(int4*)(out + i0) = make_int4(v0, v1, v2, v3);
    } else {
        for (int i = i0; i < n; ++i) out[i] = f ? ei[2 * i] : ei[i];
    }
}

// ---------------- bucketed CSR build ----------------
// Phase 1: bin edges by dst>>BSHIFT through LDS (sorted staging -> coalesced runs)
__global__ __launch_bounds__(256) void k_bin(const int* __restrict__ src,
                                             const int* __restrict__ dst, int E,
                                             int* __restrict__ gcnt, int2* __restrict__ pairs) {
    __shared__ int hist[NBUK], cnt2[NBUK], startb[NBUK], gbase[NBUK];
    __shared__ int2 stage[1024];
    int t = threadIdx.x;
    int e0 = blockIdx.x * 1024;
    int nblk = min(1024, E - e0);
    if (t < NBUK) { hist[t] = 0; cnt2[t] = 0; }
    __syncthreads();
    int2 pr[4];
    int bb[4], m = 0;
    int idx0 = e0 + t * 4;
    if (idx0 + 4 <= E) {
        int4 s = *(const int4*)(src + idx0);
        int4 d = *(const int4*)(dst + idx0);
        pr[0] = make_int2(s.x, d.x); pr[1] = make_int2(s.y, d.y);
        pr[2] = make_int2(s.z, d.z); pr[3] = make_int2(s.w, d.w);
        m = 4;
    } else {
        for (int i = idx0; i < E; ++i) pr[m++] = make_int2(src[i], dst[i]);
    }
#pragma unroll
    for (int k = 0; k < 4; k++)
        if (k < m) { bb[k] = pr[k].y >> BSHIFT; atomicAdd(&hist[bb[k]], 1); }
    __syncthreads();
    if (t < 64) {  // wave 0: inclusive shuffle-scan over 64 buckets + global reserve
        int h = hist[t], v = h;
        for (int off = 1; off < 64; off <<= 1) {
            int u = __shfl_up(v, off, 64);
            if (t >= off) v += u;
        }
        startb[t] = v - h;
        gbase[t] = h ? atomicAdd(&gcnt[t], h) : 0;
    }
    __syncthreads();
#pragma unroll
    for (int k = 0; k < 4; k++)
        if (k < m) {
            int r = atomicAdd(&cnt2[bb[k]], 1);
            stage[startb[bb[k]] + r] = pr[k];
        }
    __syncthreads();
    for (int i = t; i < nblk; i += 256) {
        int2 q = stage[i];
        int b = q.y >> BSHIFT;
        pairs[(size_t)b * BCAP + gbase[b] + (i - startb[b])] = q;
    }
}

// Phase 1.5: per-bucket degree count (atomics into a 4KB L2-local window)
__global__ void k_bdeg(const int2* __restrict__ pairs, const int* __restrict__ gcnt,
                       int* __restrict__ deg) {
    int b = blockIdx.x >> 2, sub = blockIdx.x & 3;
    int cnt = gcnt[b];
    const int2* pp = pairs + (size_t)b * BCAP;
    int i = sub * 256 + threadIdx.x;
    for (; i + 3072 < cnt; i += 4096) {
        int d0 = pp[i].y, d1 = pp[i + 1024].y, d2 = pp[i + 2048].y, d3 = pp[i + 3072].y;
        atomicAdd(&deg[d0], 1); atomicAdd(&deg[d1], 1);
        atomicAdd(&deg[d2], 1); atomicAdd(&deg[d3], 1);
    }
    for (; i < cnt; i += 1024) atomicAdd(&deg[pairs[(size_t)b * BCAP + i].y], 1);
}

// +1 inside scan accounts for the self loop (deg[] holds only real in-edges)
__global__ void k_scan1(const int* __restrict__ deg, int* rowptr, int* bsum, int N) {
    __shared__ int lds[256];
    int t = threadIdx.x, n = blockIdx.x * 256 + t;
    int v = (n < N) ? deg[n] + 1 : 0;
    int xv = v;
    lds[t] = xv;
    __syncthreads();
    for (int off = 1; off < 256; off <<= 1) {
        int tmp = (t >= off) ? lds[t - off] : 0;
        __syncthreads();
        xv += tmp;
        lds[t] = xv;
        __syncthreads();
    }
    if (n < N) rowptr[n + 1] = xv;
    if (t == 255) bsum[blockIdx.x] = xv;
}

__global__ void k_scan2(int* bsum, int nb) {
    __shared__ int lds[256];
    int t = threadIdx.x;
    int v = (t < nb) ? bsum[t] : 0;
    int xv = v;
    lds[t] = xv;
    __syncthreads();
    for (int off = 1; off < 256; off <<= 1) {
        int tmp = (t >= off) ? lds[t - off] : 0;
        __syncthreads();
        xv += tmp;
        lds[t] = xv;
        __syncthreads();
    }
    if (t < nb) bsum[t] = xv - v;  // exclusive
}

// finalize rowptr, init cursor (=rowptr[n]), and place self-loop at last slot
__global__ void k_scan3(int* rowptr, const int* __restrict__ bsum,
                        const int* __restrict__ deg, int* cursor, int* eidx, int N) {
    int n = blockIdx.x * 256 + threadIdx.x;
    if (n < N) {
        int val = rowptr[n + 1] + bsum[blockIdx.x];
        rowptr[n + 1] = val;
        cursor[n] = val - deg[n] - 1;  // == rowptr[n]
        eidx[val - 1] = n;             // self loop (atomic-free, deterministic slot)
    }
    if (n == 0) rowptr[0] = 0;
}

// Phase 2: per-bucket scatter — cursor (4KB) and eidx window (~66KB) are L2-local
__global__ void k_bscat(const int2* __restrict__ pairs, const int* __restrict__ gcnt,
                        int* __restrict__ cursor, int* __restrict__ eidx) {
    int b = blockIdx.x >> 2, sub = blockIdx.x & 3;
    int cnt = gcnt[b];
    const int2* pp = pairs + (size_t)b * BCAP;
    int i = sub * 256 + threadIdx.x;
    for (; i + 3072 < cnt; i += 4096) {
        int2 q0 = pp[i], q1 = pp[i + 1024], q2 = pp[i + 2048], q3 = pp[i + 3072];
        int p0 = atomicAdd(&cursor[q0.y], 1);
        int p1 = atomicAdd(&cursor[q1.y], 1);
        int p2 = atomicAdd(&cursor[q2.y], 1);
        int p3 = atomicAdd(&cursor[q3.y], 1);
        eidx[p0] = q0.x; eidx[p1] = q1.x; eidx[p2] = q2.x; eidx[p3] = q3.x;
    }
    for (; i < cnt; i += 1024) {
        int2 q = pp[i];
        int p = atomicAdd(&cursor[q.y], 1);
        eidx[p] = q.x;
    }
}

// ---------------- fp32 -> bf16 cast (4 elems/thread) ----------------
__global__ void k_f2b4(const float* __restrict__ in, unsigned short* __restrict__ out, int n4) {
    int i = blockIdx.x * blockDim.x + threadIdx.x;
    if (i >= n4) return;
    float4 v = ((const float4*)in)[i];
    ushort4 o = make_ushort4(f2b(v.x), f2b(v.y), f2b(v.z), f2b(v.w));
    ((ushort4*)out)[i] = o;
}

// ---------------- weight convert+transpose: WT[c][k] = W[k][c] ----------------
__global__ void k_wcvt(const float* __restrict__ W, unsigned short* __restrict__ WT,
                       int K, int M) {
    int idx = blockIdx.x * blockDim.x + threadIdx.x;
    if (idx >= K * M) return;
    int c = idx / K, k = idx - c * K;
    WT[idx] = f2b(W[(size_t)k * M + c]);
}

// W2 special: WT2[c][j] = 0.25*W2[(j&127)*512 + (j>>7)*128 + c]  (j = h*128+k; folds head-mean)
__global__ void k_w2cvt(const float* __restrict__ W2, unsigned short* __restrict__ WT2) {
    int idx = blockIdx.x * blockDim.x + threadIdx.x;
    if (idx >= 128 * 512) return;
    int c = idx >> 9, j = idx & 511;
    WT2[idx] = f2b(0.25f * W2[(size_t)(j & 127) * 512 + (j >> 7) * 128 + c]);
}

// ---------------- LDS fragment load: two 8B reads (stride-72B rows, align 8) ----------------
__device__ __forceinline__ bf16x8 lds_frag(const unsigned short* pp) {
    union { bf16x8 v; uint2 u2[2]; } t;
    t.u2[0] = *(const uint2*)pp;
    t.u2[1] = *(const uint2*)(pp + 4);
    return t.v;
}

// ---------------- tiled MFMA GEMM: out[N,128] = A16[N,K] @ W (via WT[128][K]) ----------------
// Optionally fuses per-row attention scores (layers 0/1): head of col = c>>1.
template <int K>
__global__ __launch_bounds__(256) void k_tgemm(const unsigned short* __restrict__ A,
                                               const unsigned short* __restrict__ WT,
                                               float* __restrict__ out,
                                               unsigned short* __restrict__ out16,
                                               const float* __restrict__ att_s,
                                               const float* __restrict__ att_d,
                                               float* __restrict__ a_s,
                                               float* __restrict__ a_d, int N) {
    __shared__ unsigned short Ast[64 * 36];   // [row][36] (72 B stride)
    __shared__ unsigned short Bst[128 * 36];  // [col][36]
    const int tid = threadIdx.x;
    const int lane = tid & 63, w = tid >> 6;
    const int l16 = lane & 15, quad = lane >> 4;
    const int rowbase = blockIdx.x * 64;
    const int sar = tid >> 2, sak = tid & 3;
    const int sbc = tid >> 1, sbk = tid & 1;
    const long arow_g = min(rowbase + sar, N - 1);

    floatx4 acc[8];
#pragma unroll
    for (int c = 0; c < 8; c++) acc[c] = (floatx4){0.f, 0.f, 0.f, 0.f};

    uint4 rA, rB0, rB1;
    const unsigned short* Ag = A + (size_t)arow_g * K + sak * 8;
    const unsigned short* Bg = WT + (size_t)sbc * K + sbk * 8;
    rA = *(const uint4*)(Ag);
    rB0 = *(const uint4*)(Bg);
    rB1 = *(const uint4*)(Bg + 16);

    unsigned short* Aw = Ast + sar * 36 + sak * 8;
    unsigned short* Bw0 = Bst + sbc * 36 + sbk * 8;
    unsigned short* Bw1 = Bw0 + 16;
    const unsigned short* Ar = Ast + (w * 16 + l16) * 36 + quad * 8;
    const unsigned short* Br = Bst + l16 * 36 + quad * 8;

#pragma unroll
    for (int k0 = 0; k0 < K; k0 += 32) {
        __syncthreads();
        *(uint2*)(Aw) = make_uint2(rA.x, rA.y);
        *(uint2*)(Aw + 4) = make_uint2(rA.z, rA.w);
        *(uint2*)(Bw0) = make_uint2(rB0.x, rB0.y);
        *(uint2*)(Bw0 + 4) = make_uint2(rB0.z, rB0.w);
        *(uint2*)(Bw1) = make_uint2(rB1.x, rB1.y);
        *(uint2*)(Bw1 + 4) = make_uint2(rB1.z, rB1.w);
        __syncthreads();
        if (k0 + 32 < K) {
            rA = *(const uint4*)(Ag + k0 + 32);
            rB0 = *(const uint4*)(Bg + k0 + 32);
            rB1 = *(const uint4*)(Bg + k0 + 48);
        }
        bf16x8 af = lds_frag(Ar);
#pragma unroll
        for (int c = 0; c < 8; c++) {
            bf16x8 bf = lds_frag(Br + c * 16 * 36);
            acc[c] = __builtin_amdgcn_mfma_f32_16x16x32_bf16(af, bf, acc[c], 0, 0, 0);
        }
    }

    const int row00 = rowbase + w * 16 + quad * 4;
#pragma unroll
    for (int c = 0; c < 8; c++) {
#pragma unroll
        for (int r = 0; r < 4; r++) {
            int row = row00 + r;
            if (row < N) {
                if (out) out[(size_t)row * 128 + c * 16 + l16] = acc[c][r];
                if (out16) out16[(size_t)row * 128 + c * 16 + l16] = f2b(acc[c][r]);
            }
        }
    }
    if (att_s) {
        float asc[8], adc[8];
#pragma unroll
        for (int c = 0; c < 8; c++) {
            asc[c] = att_s[c * 16 + l16];
            adc[c] = att_d[c * 16 + l16];
        }
#pragma unroll
        for (int r = 0; r < 4; r++) {
            float ts[4] = {0.f, 0.f, 0.f, 0.f}, td[4] = {0.f, 0.f, 0.f, 0.f};
#pragma unroll
            for (int c = 0; c < 8; c++) {
                ts[c >> 1] += acc[c][r] * asc[c];
                td[c >> 1] += acc[c][r] * adc[c];
            }
#pragma unroll
            for (int off = 1; off < 16; off <<= 1) {
#pragma unroll
                for (int hh = 0; hh < 4; hh++) {
                    ts[hh] += __shfl_xor(ts[hh], off, 64);
                    td[hh] += __shfl_xor(td[hh], off, 64);
                }
            }
            int row = row00 + r;
            if (l16 == 0 && row < N) {
#pragma unroll
                for (int hh = 0; hh < 4; hh++) {
                    a_s[(size_t)row * 4 + hh] = ts[hh];
                    a_d[(size_t)row * 4 + hh] = td[hh];
                }
            }
        }
    }
}

// ---------------- layer 2 score precompute ----------------
__global__ void k_makeWt(const float* __restrict__ W2, const float* __restrict__ as2,
                         const float* __restrict__ ad2, float* __restrict__ Wt) {
    int wid = (blockIdx.x * blockDim.x + threadIdx.x) >> 6;
    int lane = threadIdx.x & 63;
    if (wid >= 1024) return;
    int k = wid & 127, hh = (wid >> 7) & 3, isd = wid >> 9;
    const float* att = isd ? ad2 : as2;
    float v = W2[(size_t)k * 512 + hh * 128 + lane] * att[hh * 128 + lane] +
              W2[(size_t)k * 512 + hh * 128 + 64 + lane] * att[hh * 128 + 64 + lane];
    for (int m = 32; m >= 1; m >>= 1) v += __shfl_xor(v, m, 64);
    if (lane == 0) Wt[isd * 512 + hh * 128 + k] = v;
}

// ---------------- layer 2 scores from h ----------------
__global__ void k_attW(const float* __restrict__ hb, const float* __restrict__ Wt,
                       float* __restrict__ a_s, float* __restrict__ a_d, int N) {
    int wid = (blockIdx.x * blockDim.x + threadIdx.x) >> 6;
    int lane = threadIdx.x & 63;
    if (wid >= N) return;
    float x0 = hb[(size_t)wid * 128 + lane], x1 = hb[(size_t)wid * 128 + 64 + lane];
    float ts[4], td[4];
#pragma unroll
    for (int hh = 0; hh < 4; hh++) {
        ts[hh] = x0 * Wt[hh * 128 + lane] + x1 * Wt[hh * 128 + 64 + lane];
        td[hh] = x0 * Wt[512 + hh * 128 + lane] + x1 * Wt[512 + hh * 128 + 64 + lane];
    }
    for (int m = 32; m >= 1; m >>= 1) {
#pragma unroll
        for (int hh = 0; hh < 4; hh++) {
            ts[hh] += __shfl_xor(ts[hh], m, 64);
            td[hh] += __shfl_xor(td[hh], m, 64);
        }
    }
    if (lane == 0) {
#pragma unroll
        for (int hh = 0; hh < 4; hh++) {
            a_s[wid * 4 + hh] = ts[hh];
            a_d[wid * 4 + hh] = td[hh];
        }
    }
}

// ---------------- edge softmax weights ----------------
__global__ void k_edgew(const float* __restrict__ a_s, const float* __restrict__ a_d,
                        const int* __restrict__ rowptr, const int* __restrict__ eidx,
                        float4* __restrict__ wp, float4* __restrict__ invden, int N) {
    int d = (blockIdx.x * blockDim.x + threadIdx.x) >> 6;
    int lane = threadIdx.x & 63;
    if (d >= N) return;
    float4 ad4 = *(const float4*)(a_d + (size_t)d * 4);
    int jb = rowptr[d], je = rowptr[d + 1], deg = je - jb;
    int j = jb + lane;
    if (deg <= 64) {
        float e[4] = {-INFINITY, -INFINITY, -INFINITY, -INFINITY};
        if (j < je) {
            int s = eidx[j];
            float4 as4 = *(const float4*)(a_s + (size_t)s * 4);
#pragma unroll
            for (int hh = 0; hh < 4; hh++)
                e[hh] = lrelu(((const float*)&as4)[hh] + ((const float*)&ad4)[hh]);
        }
        float m[4] = {e[0], e[1], e[2], e[3]};
        for (int off = 32; off >= 1; off >>= 1) {
#pragma unroll
            for (int hh = 0; hh < 4; hh++) m[hh] = fmaxf(m[hh], __shfl_xor(m[hh], off, 64));
        }
        float p[4], den[4];
#pragma unroll
        for (int hh = 0; hh < 4; hh++) {
            p[hh] = (j < je) ? __expf(e[hh] - m[hh]) : 0.f;
            den[hh] = p[hh];
        }
        for (int off = 32; off >= 1; off >>= 1) {
#pragma unroll
            for (int hh = 0; hh < 4; hh++) den[hh] += __shfl_xor(den[hh], off, 64);
        }
        if (j < je) wp[j] = make_float4(p[0], p[1], p[2], p[3]);
        if (lane == 0)
            invden[d] = make_float4(1.f / (den[0] + 1e-16f), 1.f / (den[1] + 1e-16f),
                                    1.f / (den[2] + 1e-16f), 1.f / (den[3] + 1e-16f));
    } else {
        float m[4] = {-INFINITY, -INFINITY, -INFINITY, -INFINITY};
        for (int jj = j; jj < je; jj += 64) {
            int s = eidx[jj];
            float4 as4 = *(const float4*)(a_s + (size_t)s * 4);
#pragma unroll
            for (int hh = 0; hh < 4; hh++)
                m[hh] = fmaxf(m[hh], lrelu(((const float*)&as4)[hh] + ((const float*)&ad4)[hh]));
        }
        for (int off = 32; off >= 1; off >>= 1) {
#pragma unroll
            for (int hh = 0; hh < 4; hh++) m[hh] = fmaxf(m[hh], __shfl_xor(m[hh], off, 64));
        }
        float den[4] = {0.f, 0.f, 0.f, 0.f};
        for (int jj = j; jj < je; jj += 64) {
            int s = eidx[jj];
            float4 as4 = *(const float4*)(a_s + (size_t)s * 4);
            float p[4];
#pragma unroll
            for (int hh = 0; hh < 4; hh++) {
                float e = lrelu(((const float*)&as4)[hh] + ((const float*)&ad4)[hh]);
                p[hh] = __expf(e - m[hh]);
                den[hh] += p[hh];
            }
            wp[jj] = make_float4(p[0], p[1], p[2], p[3]);
        }
        for (int off = 32; off >= 1; off >>= 1) {
#pragma unroll
            for (int hh = 0; hh < 4; hh++) den[hh] += __shfl_xor(den[hh], off, 64);
        }
        if (lane == 0)
            invden[d] = make_float4(1.f / (den[0] + 1e-16f), 1.f / (den[1] + 1e-16f),
                                    1.f / (den[2] + 1e-16f), 1.f / (den[3] + 1e-16f));
    }
}

// ---------------- accumulation, layers 0/1: bf16 gather, unroll x4 for MLP ----------------
__global__ void k_acc01(const unsigned short* __restrict__ xp16, const float* __restrict__ wp,
                        const float4* __restrict__ invden, const int* __restrict__ rowptr,
                        const int* __restrict__ eidx, const float* __restrict__ bias,
                        float* __restrict__ out, int N) {
    int d = (blockIdx.x * blockDim.x + threadIdx.x) >> 6;
    int lane = threadIdx.x & 63;
    if (d >= N) return;
    int hh = lane >> 4;
    int jb = rowptr[d], je = rowptr[d + 1];
    float a0 = 0.f, a1 = 0.f;
    int j = jb;
    for (; j + 4 <= je; j += 4) {
        int s0 = __builtin_amdgcn_readfirstlane(eidx[j]);
        int s1 = __builtin_amdgcn_readfirstlane(eidx[j + 1]);
        int s2 = __builtin_amdgcn_readfirstlane(eidx[j + 2]);
        int s3 = __builtin_amdgcn_readfirstlane(eidx[j + 3]);
        float w0 = wp[(size_t)j * 4 + hh];
        float w1 = wp[(size_t)(j + 1) * 4 + hh];
        float w2 = wp[(size_t)(j + 2) * 4 + hh];
        float w3 = wp[(size_t)(j + 3) * 4 + hh];
        unsigned int u0 = *(const unsigned int*)(xp16 + (size_t)s0 * 128 + 2 * lane);
        unsigned int u1 = *(const unsigned int*)(xp16 + (size_t)s1 * 128 + 2 * lane);
        unsigned int u2 = *(const unsigned int*)(xp16 + (size_t)s2 * 128 + 2 * lane);
        unsigned int u3 = *(const unsigned int*)(xp16 + (size_t)s3 * 128 + 2 * lane);
        a0 += w0 * b2f_lo(u0) + w1 * b2f_lo(u1) + w2 * b2f_lo(u2) + w3 * b2f_lo(u3);
        a1 += w0 * b2f_hi(u0) + w1 * b2f_hi(u1) + w2 * b2f_hi(u2) + w3 * b2f_hi(u3);
    }
    for (; j < je; ++j) {
        int s = __builtin_amdgcn_readfirstlane(eidx[j]);
        float w = wp[(size_t)j * 4 + hh];
        unsigned int u = *(const unsigned int*)(xp16 + (size_t)s * 128 + 2 * lane);
        a0 += w * b2f_lo(u);
        a1 += w * b2f_hi(u);
    }
    float inv = ((const float*)(invden + d))[hh];
    float2 o = make_float2(a0 * inv + bias[2 * lane], a1 * inv + bias[2 * lane + 1]);
    *(float2*)(out + (size_t)d * 128 + 2 * lane) = o;
}

// ---------------- accumulation, layer 2: bf16 gather shared by 4 heads, unroll x4 ----------------
__global__ void k_accL2(const unsigned short* __restrict__ hb16, const float4* __restrict__ wp,
                        const float4* __restrict__ invden, const int* __restrict__ rowptr,
                        const int* __restrict__ eidx, unsigned short* __restrict__ agg16,
                        int N) {
    int d = (blockIdx.x * blockDim.x + threadIdx.x) >> 6;
    int lane = threadIdx.x & 63;
    if (d >= N) return;
    int jb = rowptr[d], je = rowptr[d + 1];
    float acc[4][2] = {{0.f, 0.f}, {0.f, 0.f}, {0.f, 0.f}, {0.f, 0.f}};
    int j = jb;
    for (; j + 4 <= je; j += 4) {
        int s0 = __builtin_amdgcn_readfirstlane(eidx[j]);
        int s1 = __builtin_amdgcn_readfirstlane(eidx[j + 1]);
        int s2 = __builtin_amdgcn_readfirstlane(eidx[j + 2]);
        int s3 = __builtin_amdgcn_readfirstlane(eidx[j + 3]);
        float4 w0 = wp[j], w1 = wp[j + 1], w2 = wp[j + 2], w3 = wp[j + 3];
        unsigned int u0 = *(const unsigned int*)(hb16 + (size_t)s0 * 128 + 2 * lane);
        unsigned int u1 = *(const unsigned int*)(hb16 + (size_t)s1 * 128 + 2 * lane);
        unsigned int u2 = *(const unsigned int*)(hb16 + (size_t)s2 * 128 + 2 * lane);
        unsigned int u3 = *(const unsigned int*)(hb16 + (size_t)s3 * 128 + 2 * lane);
        float lo0 = b2f_lo(u0), hi0 = b2f_hi(u0);
        float lo1 = b2f_lo(u1), hi1 = b2f_hi(u1);
        float lo2 = b2f_lo(u2), hi2 = b2f_hi(u2);
        float lo3 = b2f_lo(u3), hi3 = b2f_hi(u3);
#pragma unroll
        for (int hh = 0; hh < 4; hh++) {
            acc[hh][0] += ((const float*)&w0)[hh] * lo0 + ((const float*)&w1)[hh] * lo1 +
                          ((const float*)&w2)[hh] * lo2 + ((const float*)&w3)[hh] * lo3;
            acc[hh][1] += ((const float*)&w0)[hh] * hi0 + ((const float*)&w1)[hh] * hi1 +
                          ((const float*)&w2)[hh] * hi2 + ((const float*)&w3)[hh] * hi3;
        }
    }
    for (; j < je; ++j) {
        int s = __builtin_amdgcn_readfirstlane(eidx[j]);
        float4 w = wp[j];
        unsigned int u = *(const unsigned int*)(hb16 + (size_t)s * 128 + 2 * lane);
        float lo = b2f_lo(u), hi = b2f_hi(u);
#pragma unroll
        for (int hh = 0; hh < 4; hh++) {
            acc[hh][0] += ((const float*)&w)[hh] * lo;
            acc[hh][1] += ((const float*)&w)[hh] * hi;
        }
    }
    float4 inv = invden[d];
#pragma unroll
    for (int hh = 0; hh < 4; hh++) {
        float iv = ((const float*)&inv)[hh];
        ushort2 o = make_ushort2(f2b(acc[hh][0] * iv), f2b(acc[hh][1] * iv));
        *(ushort2*)(agg16 + (size_t)d * 512 + hh * 128 + 2 * lane) = o;
    }
}

// ---------------- batch norm ----------------
__global__ void k_bnstats(const float* __restrict__ x, float* __restrict__ sums, int N) {
    int col = threadIdx.x & 127, half = threadIdx.x >> 7;
    float s1 = 0.f, s2 = 0.f;
    for (int r = blockIdx.x * 2 + half; r < N; r += gridDim.x * 2) {
        float v = x[(size_t)r * 128 + col];
        s1 += v;
        s2 += v * v;
    }
    atomicAdd(&sums[col], s1);
    atomicAdd(&sums[128 + col], s2);
}

// normalize (+ELU) in place; optionally also emit bf16 copy for the next GEMM
__global__ void k_bnapply(float* __restrict__ x, unsigned short* __restrict__ out16,
                          const float* __restrict__ sums, const float* __restrict__ gamma,
                          const float* __restrict__ beta, int N, int elu) {
    int idx = blockIdx.x * blockDim.x + threadIdx.x;  // float4 index
    if (idx >= N * 32) return;
    float4 v = ((float4*)x)[idx];
    int colb = (idx & 31) * 4;
    float invN = 1.f / (float)N;
#pragma unroll
    for (int j = 0; j < 4; j++) {
        int col = colb + j;
        float mu = sums[col] * invN;
        float var = sums[128 + col] * invN - mu * mu;
        float y = (((float*)&v)[j] - mu) * rsqrtf(var + EPS_BN) * gamma[col] + beta[col];
        if (elu) y = y > 0.f ? y : __expf(y) - 1.f;
        ((float*)&v)[j] = y;
    }
    ((float4*)x)[idx] = v;
    if (out16) {
        ushort4 o = make_ushort4(f2b(v.x), f2b(v.y), f2b(v.z), f2b(v.w));
        ((ushort4*)out16)[idx] = o;
    }
}

// ---------------- launch ----------------
extern "C" void kernel_launch(void* const* d_in, const int* in_sizes, int n_in,
                              void* d_out, int out_size, void* d_ws, size_t ws_size,
                              hipStream_t stream) {
    const float* x = (const float*)d_in[0];
    const int* ei_raw = (const int*)d_in[1];
    const float* W0 = (const float*)d_in[2];
    const float* as0 = (const float*)d_in[3];
    const float* ad0 = (const float*)d_in[4];
    const float* b0 = (const float*)d_in[5];
    const float* g0 = (const float*)d_in[6];
    const float* be0 = (const float*)d_in[7];
    const float* W1 = (const float*)d_in[8];
    const float* as1 = (const float*)d_in[9];
    const float* ad1 = (const float*)d_in[10];
    const float* b1 = (const float*)d_in[11];
    const float* g1 = (const float*)d_in[12];
    const float* be1 = (const float*)d_in[13];
    const float* W2 = (const float*)d_in[14];
    const float* as2 = (const float*)d_in[15];
    const float* ad2 = (const float*)d_in[16];
    const float* g2v = (const float*)d_in[18];
    const float* be2 = (const float*)d_in[19];

    const int N = in_sizes[0] / 128;
    const int E = in_sizes[1] / 2;

    // workspace carve (256B aligned)
    char* p = (char*)d_ws;
    auto alloc = [&](size_t bytes) {
        void* r = (void*)p;
        p += (bytes + 255) & ~(size_t)255;
        return r;
    };
    float* hbuf = (float*)alloc((size_t)N * 128 * 4);    // hidden (fp32)
    unsigned short* xb = (unsigned short*)alloc((size_t)N * 128 * 2);    // bf16 of x
    unsigned short* xp16 = (unsigned short*)alloc((size_t)N * 128 * 2);  // bf16 projected feats
    unsigned short* hb16 = (unsigned short*)alloc((size_t)N * 128 * 2);  // bf16 of hbuf
    unsigned short* agg16 = (unsigned short*)alloc((size_t)N * 512 * 2); // bf16 layer-2 aggregate
    float* As = (float*)alloc((size_t)N * 4 * 4);
    float* Ad = (float*)alloc((size_t)N * 4 * 4);
    int* deg = (int*)alloc((size_t)N * 4);
    int* rowptr = (int*)alloc((size_t)(N + 1) * 4);
    int* cursor = (int*)alloc((size_t)N * 4);
    int* bsum = (int*)alloc(1024);
    int* eidx = (int*)alloc((size_t)(E + N) * 4);
    float* bns = (float*)alloc(256 * 4);
    // union: ei32 (2E ints, CSR build only) then wp ((E+N) float4)
    size_t uni_bytes = (size_t)(E + N) * 16;
    size_t ei_bytes = (size_t)2 * E * 4;
    char* uni = (char*)alloc(uni_bytes > ei_bytes ? uni_bytes : ei_bytes);
    int* ei32 = (int*)uni;
    float4* wp = (float4*)uni;
    float4* invden = (float4*)alloc((size_t)N * 16);
    int* flag = (int*)alloc(256);
    float* Wt = (float*)alloc(1024 * 4);
    unsigned short* WT0 = (unsigned short*)alloc((size_t)128 * 128 * 2);
    unsigned short* WT1 = (unsigned short*)alloc((size_t)128 * 128 * 2);
    unsigned short* WT2 = (unsigned short*)alloc((size_t)128 * 512 * 2);
    int2* pairs = (int2*)alloc((size_t)NBUK * BCAP * 8);  // bucketed (src,dst)
    int* gcnt = (int*)alloc(NBUK * 4);
    if ((size_t)(p - (char*)d_ws) > ws_size) return;

    const int nb = (N + 255) / 256;
    const int gw = (N + 3) / 4;              // wave-per-node kernels
    const int gt = (N + 63) / 64;            // tiled GEMM: 64 rows per block
    const int nbuk_used = (N + (1 << BSHIFT) - 1) >> BSHIFT;

    // --- edge dtype normalize ---
    k_detect64<<<1, 64, 0, stream>>>(ei_raw, flag, 2 * E);
    k_convert<<<(2 * E + 1023) / 1024, 256, 0, stream>>>(ei_raw, flag, ei32, 2 * E);
    const int* srcv = ei32;
    const int* dstv = ei32 + E;

    // --- bucketed CSR build ---
    hipMemsetAsync(gcnt, 0, NBUK * 4, stream);
    hipMemsetAsync(deg, 0, (size_t)N * 4, stream);
    k_bin<<<(E + 1023) / 1024, 256, 0, stream>>>(srcv, dstv, E, gcnt, pairs);
    k_bdeg<<<nbuk_used * 4, 256, 0, stream>>>(pairs, gcnt, deg);
    k_scan1<<<nb, 256, 0, stream>>>(deg, rowptr, bsum, N);
    k_scan2<<<1, 256, 0, stream>>>(bsum, nb);
    k_scan3<<<nb, 256, 0, stream>>>(rowptr, bsum, deg, cursor, eidx, N);
    k_bscat<<<nbuk_used * 4, 256, 0, stream>>>(pairs, gcnt, cursor, eidx);

    // --- weight prep (bf16 transposed) + input cast ---
    k_wcvt<<<(128 * 128 + 255) / 256, 256, 0, stream>>>(W0, WT0, 128, 128);
    k_wcvt<<<(128 * 128 + 255) / 256, 256, 0, stream>>>(W1, WT1, 128, 128);
    k_w2cvt<<<(128 * 512 + 255) / 256, 256, 0, stream>>>(W2, WT2);
    k_makeWt<<<256, 256, 0, stream>>>(W2, as2, ad2, Wt);
    k_f2b4<<<(N * 32 + 255) / 256, 256, 0, stream>>>(x, xb, N * 32);

    // --- layer 0 (GEMM fuses attention scores) ---
    k_tgemm<128><<<gt, 256, 0, stream>>>(xb, WT0, (float*)nullptr, xp16, as0, ad0, As, Ad, N);
    k_edgew<<<gw, 256, 0, stream>>>(As, Ad, rowptr, eidx, wp, invden, N);
    k_acc01<<<gw, 256, 0, stream>>>(xp16, (const float*)wp, invden, rowptr, eidx, b0, hbuf, N);
    hipMemsetAsync(bns, 0, 256 * 4, stream);
    k_bnstats<<<256, 256, 0, stream>>>(hbuf, bns, N);
    k_bnapply<<<(N * 32 + 255) / 256, 256, 0, stream>>>(hbuf, hb16, bns, g0, be0, N, 1);

    // --- layer 1 ---
    k_tgemm<128><<<gt, 256, 0, stream>>>(hb16, WT1, (float*)nullptr, xp16, as1, ad1, As, Ad, N);
    k_edgew<<<gw, 256, 0, stream>>>(As, Ad, rowptr, eidx, wp, invden, N);
    k_acc01<<<gw, 256, 0, stream>>>(xp16, (const float*)wp, invden, rowptr, eidx, b1, hbuf, N);
    hipMemsetAsync(bns, 0, 256 * 4, stream);
    k_bnstats<<<256, 256, 0, stream>>>(hbuf, bns, N);
    k_bnapply<<<(N * 32 + 255) / 256, 256, 0, stream>>>(hbuf, hb16, bns, g1, be1, N, 1);

    // --- layer 2 (linearity: aggregate h per head, then [N,512]@[512,128] MFMA GEMM) ---
    float* outf = (float*)d_out;
    k_attW<<<gw, 256, 0, stream>>>(hbuf, Wt, As, Ad, N);
    k_edgew<<<gw, 256, 0, stream>>>(As, Ad, rowptr, eidx, wp, invden, N);
    k_accL2<<<gw, 256, 0, stream>>>(hb16, wp, invden, rowptr, eidx, agg16, N);
    k_tgemm<512><<<gt, 256, 0, stream>>>(agg16, WT2, outf, (unsigned short*)nullptr,
                                         (const float*)nullptr, (const float*)nullptr,
                                         (float*)nullptr, (float*)nullptr, N);
    hipMemsetAsync(bns, 0, 256 * 4, stream);
    k_bnstats<<<256, 256, 0, stream>>>(outf, bns, N);
    k_bnapply<<<(N * 32 + 255) / 256, 256, 0, stream>>>(outf, (unsigned short*)nullptr, bns, g2v, be2, N, 0);
}

// Round 10
// 611.837 us; speedup vs baseline: 1.1121x; 1.1121x over previous
//
#include <hip/hip_runtime.h>
#include <math.h>

#define EPS_BN 1e-5f
#define NBUK 128
#define BSHIFT 9
#define BCAP 16384
#define SCAP 14336

typedef __bf16 bf16x8 __attribute__((ext_vector_type(8)));
typedef float floatx4 __attribute__((ext_vector_type(4)));

__device__ __forceinline__ float lrelu(float x) { return x > 0.f ? x : 0.2f * x; }

__device__ __forceinline__ unsigned short f2b(float f) {
    unsigned int b = __float_as_uint(f);
    b = (b + 0x7fffu + ((b >> 16) & 1u)) >> 16;
    return (unsigned short)b;
}
__device__ __forceinline__ float b2f_lo(unsigned int u) { return __uint_as_float(u << 16); }
__device__ __forceinline__ float b2f_hi(unsigned int u) { return __uint_as_float(u & 0xffff0000u); }

// ---------------- edge dtype probe ----------------
__global__ void k_detect64(const int* __restrict__ ei, int* flag, int nwords) {
    int lane = threadIdx.x;  // 64
    int lim = nwords < 512 ? nwords : 512;
    int zeros = 0;
    for (int i = 2 * lane + 1; i < lim; i += 128) zeros += (ei[i] == 0);
    for (int off = 32; off >= 1; off >>= 1) zeros += __shfl_xor(zeros, off, 64);
    if (lane == 0) *flag = (zeros > lim / 8) ? 1 : 0;
}

// ---------------- bucketed CSR build ----------------
// Phase 1: bin edges by dst>>BSHIFT through LDS (fused int64->int32 convert)
__global__ __launch_bounds__(256) void k_bin(const int* __restrict__ ei,
                                             const int* __restrict__ flag, int E,
                                             int* __restrict__ gcnt, int2* __restrict__ pairs) {
    __shared__ int hist[NBUK], cnt2[NBUK], startb[NBUK], gbase[NBUK], sc[NBUK];
    __shared__ int2 stage[1024];
    int t = threadIdx.x;
    int e0 = blockIdx.x * 1024;
    int nblk = min(1024, E - e0);
    int f = *flag;
    if (t < NBUK) { hist[t] = 0; cnt2[t] = 0; }
    __syncthreads();
    int2 pr[4];
    int bb[4], m = 0;
    int idx0 = e0 + t * 4;
    if (idx0 + 4 <= E) {
        int4 s, d;
        if (f) {
            s = make_int4(ei[2 * idx0], ei[2 * idx0 + 2], ei[2 * idx0 + 4], ei[2 * idx0 + 6]);
            d = make_int4(ei[2 * (E + idx0)], ei[2 * (E + idx0) + 2],
                          ei[2 * (E + idx0) + 4], ei[2 * (E + idx0) + 6]);
        } else {
            s = *(const int4*)(ei + idx0);
            d = *(const int4*)(ei + E + idx0);
        }
        pr[0] = make_int2(s.x, d.x); pr[1] = make_int2(s.y, d.y);
        pr[2] = make_int2(s.z, d.z); pr[3] = make_int2(s.w, d.w);
        m = 4;
    } else {
        for (int i = idx0; i < E; ++i)
            pr[m++] = make_int2(f ? ei[2 * i] : ei[i], f ? ei[2 * (E + i)] : ei[E + i]);
    }
#pragma unroll
    for (int k = 0; k < 4; k++)
        if (k < m) { bb[k] = pr[k].y >> BSHIFT; atomicAdd(&hist[bb[k]], 1); }
    __syncthreads();
    if (t < NBUK) sc[t] = hist[t];
    __syncthreads();
    for (int off = 1; off < NBUK; off <<= 1) {
        int v = 0;
        if (t < NBUK && t >= off) v = sc[t - off];
        __syncthreads();
        if (t < NBUK) sc[t] += v;
        __syncthreads();
    }
    if (t < NBUK) {
        startb[t] = sc[t] - hist[t];
        gbase[t] = hist[t] ? atomicAdd(&gcnt[t], hist[t]) : 0;
    }
    __syncthreads();
#pragma unroll
    for (int k = 0; k < 4; k++)
        if (k < m) {
            int r = atomicAdd(&cnt2[bb[k]], 1);
            stage[startb[bb[k]] + r] = pr[k];
        }
    __syncthreads();
    for (int i = t; i < nblk; i += 256) {
        int2 q = stage[i];
        int b = q.y >> BSHIFT;
        pairs[(size_t)b * BCAP + gbase[b] + (i - startb[b])] = q;
    }
}

// Phase 1.5: one block per bucket — LDS histogram, coalesced deg write (no global atomics)
__global__ __launch_bounds__(256) void k_bdeg2(const int2* __restrict__ pairs,
                                               const int* __restrict__ gcnt,
                                               int* __restrict__ deg, int N) {
    __shared__ int hist[512];
    int t = threadIdx.x, b = blockIdx.x, d0 = b << BSHIFT;
    hist[t] = 0; hist[t + 256] = 0;
    __syncthreads();
    int cnt = gcnt[b];
    const int2* pp = pairs + (size_t)b * BCAP;
    for (int i = t; i < cnt; i += 256) atomicAdd(&hist[pp[i].y - d0], 1);
    __syncthreads();
    if (d0 + t < N) deg[d0 + t] = hist[t];
    if (d0 + t + 256 < N) deg[d0 + t + 256] = hist[t + 256];
}

// +1 inside scan accounts for the self loop
__global__ void k_scan1(const int* __restrict__ deg, int* rowptr, int* bsum, int N) {
    __shared__ int lds[256];
    int t = threadIdx.x, n = blockIdx.x * 256 + t;
    int v = (n < N) ? deg[n] + 1 : 0;
    int xv = v;
    lds[t] = xv;
    __syncthreads();
    for (int off = 1; off < 256; off <<= 1) {
        int tmp = (t >= off) ? lds[t - off] : 0;
        __syncthreads();
        xv += tmp;
        lds[t] = xv;
        __syncthreads();
    }
    if (n < N) rowptr[n + 1] = xv;
    if (t == 255) bsum[blockIdx.x] = xv;
}

__global__ void k_scan2(int* bsum, int nb) {
    __shared__ int lds[256];
    int t = threadIdx.x;
    int v = (t < nb) ? bsum[t] : 0;
    int xv = v;
    lds[t] = xv;
    __syncthreads();
    for (int off = 1; off < 256; off <<= 1) {
        int tmp = (t >= off) ? lds[t - off] : 0;
        __syncthreads();
        xv += tmp;
        lds[t] = xv;
        __syncthreads();
    }
    if (t < nb) bsum[t] = xv - v;  // exclusive
}

__global__ void k_scan3(int* rowptr, const int* __restrict__ bsum, int N) {
    int n = blockIdx.x * 256 + threadIdx.x;
    if (n < N) rowptr[n + 1] += bsum[blockIdx.x];
    if (n == 0) rowptr[0] = 0;
}

// Phase 2: one block per bucket — build the bucket's eidx segment entirely in LDS
// (random stores stay on-CU), then write out coalesced. Fallback for extreme skew.
__global__ __launch_bounds__(256) void k_bsort(const int2* __restrict__ pairs,
                                               const int* __restrict__ gcnt,
                                               const int* __restrict__ rowptr,
                                               int* __restrict__ eidx, int N) {
    __shared__ int curs[512];
    __shared__ int simg[SCAP];
    int t = threadIdx.x, b = blockIdx.x, d0 = b << BSHIFT;
    int d1 = min(d0 + 512, N);
    int seg0 = rowptr[d0], seg1 = rowptr[d1];
    int span = seg1 - seg0;
    int cnt = gcnt[b];
    const int2* pp = pairs + (size_t)b * BCAP;
    if (span <= SCAP) {
        for (int idx = t; idx < d1 - d0; idx += 256) {
            int rb = rowptr[d0 + idx], re = rowptr[d0 + idx + 1];
            curs[idx] = rb - seg0;
            simg[re - 1 - seg0] = d0 + idx;  // self loop at last slot
        }
        __syncthreads();
        for (int i = t; i < cnt; i += 256) {
            int2 q = pp[i];
            int r = atomicAdd(&curs[q.y - d0], 1);
            simg[r] = q.x;
        }
        __syncthreads();
        for (int i = t; i < span; i += 256) eidx[seg0 + i] = simg[i];
    } else {
        for (int idx = t; idx < d1 - d0; idx += 256) {
            curs[idx] = rowptr[d0 + idx];
            eidx[rowptr[d0 + idx + 1] - 1] = d0 + idx;
        }
        __syncthreads();
        for (int i = t; i < cnt; i += 256) {
            int2 q = pp[i];
            int r = atomicAdd(&curs[q.y - d0], 1);
            eidx[r] = q.x;
        }
    }
}

// ---------------- fp32 -> bf16 cast ----------------
__global__ void k_f2b4(const float* __restrict__ in, unsigned short* __restrict__ out, int n4) {
    int i = blockIdx.x * blockDim.x + threadIdx.x;
    if (i >= n4) return;
    float4 v = ((const float4*)in)[i];
    ushort4 o = make_ushort4(f2b(v.x), f2b(v.y), f2b(v.z), f2b(v.w));
    ((ushort4*)out)[i] = o;
}

// ---------------- weight convert+transpose: WT[c][k] = W[k][c] ----------------
__global__ void k_wcvt(const float* __restrict__ W, unsigned short* __restrict__ WT,
                       int K, int M) {
    int idx = blockIdx.x * blockDim.x + threadIdx.x;
    if (idx >= K * M) return;
    int c = idx / K, k = idx - c * K;
    WT[idx] = f2b(W[(size_t)k * M + c]);
}

// W2 special: WT2[c][j] = 0.25*W2[(j&127)*512 + (j>>7)*128 + c]
__global__ void k_w2cvt(const float* __restrict__ W2, unsigned short* __restrict__ WT2) {
    int idx = blockIdx.x * blockDim.x + threadIdx.x;
    if (idx >= 128 * 512) return;
    int c = idx >> 9, j = idx & 511;
    WT2[idx] = f2b(0.25f * W2[(size_t)(j & 127) * 512 + (j >> 7) * 128 + c]);
}

// ---------------- LDS fragment load ----------------
__device__ __forceinline__ bf16x8 lds_frag(const unsigned short* pp) {
    union { bf16x8 v; uint2 u2[2]; } t;
    t.u2[0] = *(const uint2*)pp;
    t.u2[1] = *(const uint2*)(pp + 4);
    return t.v;
}

// ---------------- tiled MFMA GEMM (optional fused attention scores) ----------------
template <int K>
__global__ __launch_bounds__(256) void k_tgemm(const unsigned short* __restrict__ A,
                                               const unsigned short* __restrict__ WT,
                                               float* __restrict__ out,
                                               unsigned short* __restrict__ out16,
                                               const float* __restrict__ att_s,
                                               const float* __restrict__ att_d,
                                               float* __restrict__ a_s,
                                               float* __restrict__ a_d, int N) {
    __shared__ unsigned short Ast[64 * 36];
    __shared__ unsigned short Bst[128 * 36];
    const int tid = threadIdx.x;
    const int lane = tid & 63, w = tid >> 6;
    const int l16 = lane & 15, quad = lane >> 4;
    const int rowbase = blockIdx.x * 64;
    const int sar = tid >> 2, sak = tid & 3;
    const int sbc = tid >> 1, sbk = tid & 1;
    const long arow_g = min(rowbase + sar, N - 1);

    floatx4 acc[8];
#pragma unroll
    for (int c = 0; c < 8; c++) acc[c] = (floatx4){0.f, 0.f, 0.f, 0.f};

    uint4 rA, rB0, rB1;
    const unsigned short* Ag = A + (size_t)arow_g * K + sak * 8;
    const unsigned short* Bg = WT + (size_t)sbc * K + sbk * 8;
    rA = *(const uint4*)(Ag);
    rB0 = *(const uint4*)(Bg);
    rB1 = *(const uint4*)(Bg + 16);

    unsigned short* Aw = Ast + sar * 36 + sak * 8;
    unsigned short* Bw0 = Bst + sbc * 36 + sbk * 8;
    unsigned short* Bw1 = Bw0 + 16;
    const unsigned short* Ar = Ast + (w * 16 + l16) * 36 + quad * 8;
    const unsigned short* Br = Bst + l16 * 36 + quad * 8;

#pragma unroll
    for (int k0 = 0; k0 < K; k0 += 32) {
        __syncthreads();
        *(uint2*)(Aw) = make_uint2(rA.x, rA.y);
        *(uint2*)(Aw + 4) = make_uint2(rA.z, rA.w);
        *(uint2*)(Bw0) = make_uint2(rB0.x, rB0.y);
        *(uint2*)(Bw0 + 4) = make_uint2(rB0.z, rB0.w);
        *(uint2*)(Bw1) = make_uint2(rB1.x, rB1.y);
        *(uint2*)(Bw1 + 4) = make_uint2(rB1.z, rB1.w);
        __syncthreads();
        if (k0 + 32 < K) {
            rA = *(const uint4*)(Ag + k0 + 32);
            rB0 = *(const uint4*)(Bg + k0 + 32);
            rB1 = *(const uint4*)(Bg + k0 + 48);
        }
        bf16x8 af = lds_frag(Ar);
#pragma unroll
        for (int c = 0; c < 8; c++) {
            bf16x8 bf = lds_frag(Br + c * 16 * 36);
            acc[c] = __builtin_amdgcn_mfma_f32_16x16x32_bf16(af, bf, acc[c], 0, 0, 0);
        }
    }

    const int row00 = rowbase + w * 16 + quad * 4;
#pragma unroll
    for (int c = 0; c < 8; c++) {
#pragma unroll
        for (int r = 0; r < 4; r++) {
            int row = row00 + r;
            if (row < N) {
                if (out) out[(size_t)row * 128 + c * 16 + l16] = acc[c][r];
                if (out16) out16[(size_t)row * 128 + c * 16 + l16] = f2b(acc[c][r]);
            }
        }
    }
    if (att_s) {
        float asc[8], adc[8];
#pragma unroll
        for (int c = 0; c < 8; c++) {
            asc[c] = att_s[c * 16 + l16];
            adc[c] = att_d[c * 16 + l16];
        }
#pragma unroll
        for (int r = 0; r < 4; r++) {
            float ts[4] = {0.f, 0.f, 0.f, 0.f}, td[4] = {0.f, 0.f, 0.f, 0.f};
#pragma unroll
            for (int c = 0; c < 8; c++) {
                ts[c >> 1] += acc[c][r] * asc[c];
                td[c >> 1] += acc[c][r] * adc[c];
            }
#pragma unroll
            for (int off = 1; off < 16; off <<= 1) {
#pragma unroll
                for (int hh = 0; hh < 4; hh++) {
                    ts[hh] += __shfl_xor(ts[hh], off, 64);
                    td[hh] += __shfl_xor(td[hh], off, 64);
                }
            }
            int row = row00 + r;
            if (l16 == 0 && row < N) {
#pragma unroll
                for (int hh = 0; hh < 4; hh++) {
                    a_s[(size_t)row * 4 + hh] = ts[hh];
                    a_d[(size_t)row * 4 + hh] = td[hh];
                }
            }
        }
    }
}

// ---------------- layer 2 score precompute ----------------
__global__ void k_makeWt(const float* __restrict__ W2, const float* __restrict__ as2,
                         const float* __restrict__ ad2, float* __restrict__ Wt) {
    int wid = (blockIdx.x * blockDim.x + threadIdx.x) >> 6;
    int lane = threadIdx.x & 63;
    if (wid >= 1024) return;
    int k = wid & 127, hh = (wid >> 7) & 3, isd = wid >> 9;
    const float* att = isd ? ad2 : as2;
    float v = W2[(size_t)k * 512 + hh * 128 + lane] * att[hh * 128 + lane] +
              W2[(size_t)k * 512 + hh * 128 + 64 + lane] * att[hh * 128 + 64 + lane];
    for (int m = 32; m >= 1; m >>= 1) v += __shfl_xor(v, m, 64);
    if (lane == 0) Wt[isd * 512 + hh * 128 + k] = v;
}

// ---------------- layer 2 scores from h ----------------
__global__ void k_attW(const float* __restrict__ hb, const float* __restrict__ Wt,
                       float* __restrict__ a_s, float* __restrict__ a_d, int N) {
    int wid = (blockIdx.x * blockDim.x + threadIdx.x) >> 6;
    int lane = threadIdx.x & 63;
    if (wid >= N) return;
    float x0 = hb[(size_t)wid * 128 + lane], x1 = hb[(size_t)wid * 128 + 64 + lane];
    float ts[4], td[4];
#pragma unroll
    for (int hh = 0; hh < 4; hh++) {
        ts[hh] = x0 * Wt[hh * 128 + lane] + x1 * Wt[hh * 128 + 64 + lane];
        td[hh] = x0 * Wt[512 + hh * 128 + lane] + x1 * Wt[512 + hh * 128 + 64 + lane];
    }
    for (int m = 32; m >= 1; m >>= 1) {
#pragma unroll
        for (int hh = 0; hh < 4; hh++) {
            ts[hh] += __shfl_xor(ts[hh], m, 64);
            td[hh] += __shfl_xor(td[hh], m, 64);
        }
    }
    if (lane == 0) {
#pragma unroll
        for (int hh = 0; hh < 4; hh++) {
            a_s[wid * 4 + hh] = ts[hh];
            a_d[wid * 4 + hh] = td[hh];
        }
    }
}

// ---------------- edge softmax weights ----------------
__global__ void k_edgew(const float* __restrict__ a_s, const float* __restrict__ a_d,
                        const int* __restrict__ rowptr, const int* __restrict__ eidx,
                        float4* __restrict__ wp, float4* __restrict__ invden, int N) {
    int d = (blockIdx.x * blockDim.x + threadIdx.x) >> 6;
    int lane = threadIdx.x & 63;
    if (d >= N) return;
    float4 ad4 = *(const float4*)(a_d + (size_t)d * 4);
    int jb = rowptr[d], je = rowptr[d + 1], deg = je - jb;
    int j = jb + lane;
    if (deg <= 64) {
        float e[4] = {-INFINITY, -INFINITY, -INFINITY, -INFINITY};
        if (j < je) {
            int s = eidx[j];
            float4 as4 = *(const float4*)(a_s + (size_t)s * 4);
#pragma unroll
            for (int hh = 0; hh < 4; hh++)
                e[hh] = lrelu(((const float*)&as4)[hh] + ((const float*)&ad4)[hh]);
        }
        float m[4] = {e[0], e[1], e[2], e[3]};
        for (int off = 32; off >= 1; off >>= 1) {
#pragma unroll
            for (int hh = 0; hh < 4; hh++) m[hh] = fmaxf(m[hh], __shfl_xor(m[hh], off, 64));
        }
        float p[4], den[4];
#pragma unroll
        for (int hh = 0; hh < 4; hh++) {
            p[hh] = (j < je) ? __expf(e[hh] - m[hh]) : 0.f;
            den[hh] = p[hh];
        }
        for (int off = 32; off >= 1; off >>= 1) {
#pragma unroll
            for (int hh = 0; hh < 4; hh++) den[hh] += __shfl_xor(den[hh], off, 64);
        }
        if (j < je) wp[j] = make_float4(p[0], p[1], p[2], p[3]);
        if (lane == 0)
            invden[d] = make_float4(1.f / (den[0] + 1e-16f), 1.f / (den[1] + 1e-16f),
                                    1.f / (den[2] + 1e-16f), 1.f / (den[3] + 1e-16f));
    } else {
        float m[4] = {-INFINITY, -INFINITY, -INFINITY, -INFINITY};
        for (int jj = j; jj < je; jj += 64) {
            int s = eidx[jj];
            float4 as4 = *(const float4*)(a_s + (size_t)s * 4);
#pragma unroll
            for (int hh = 0; hh < 4; hh++)
                m[hh] = fmaxf(m[hh], lrelu(((const float*)&as4)[hh] + ((const float*)&ad4)[hh]));
        }
        for (int off = 32; off >= 1; off >>= 1) {
#pragma unroll
            for (int hh = 0; hh < 4; hh++) m[hh] = fmaxf(m[hh], __shfl_xor(m[hh], off, 64));
        }
        float den[4] = {0.f, 0.f, 0.f, 0.f};
        for (int jj = j; jj < je; jj += 64) {
            int s = eidx[jj];
            float4 as4 = *(const float4*)(a_s + (size_t)s * 4);
            float p[4];
#pragma unroll
            for (int hh = 0; hh < 4; hh++) {
                float e = lrelu(((const float*)&as4)[hh] + ((const float*)&ad4)[hh]);
                p[hh] = __expf(e - m[hh]);
                den[hh] += p[hh];
            }
            wp[jj] = make_float4(p[0], p[1], p[2], p[3]);
        }
        for (int off = 32; off >= 1; off >>= 1) {
#pragma unroll
            for (int hh = 0; hh < 4; hh++) den[hh] += __shfl_xor(den[hh], off, 64);
        }
        if (lane == 0)
            invden[d] = make_float4(1.f / (den[0] + 1e-16f), 1.f / (den[1] + 1e-16f),
                                    1.f / (den[2] + 1e-16f), 1.f / (den[3] + 1e-16f));
    }
}

// ---------------- accumulation, layers 0/1 ----------------
__global__ void k_acc01(const unsigned short* __restrict__ xp16, const float* __restrict__ wp,
                        const float4* __restrict__ invden, const int* __restrict__ rowptr,
                        const int* __restrict__ eidx, const float* __restrict__ bias,
                        float* __restrict__ out, int N) {
    int d = (blockIdx.x * blockDim.x + threadIdx.x) >> 6;
    int lane = threadIdx.x & 63;
    if (d >= N) return;
    int hh = lane >> 4;
    int jb = rowptr[d], je = rowptr[d + 1];
    float a0 = 0.f, a1 = 0.f;
    int j = jb;
    for (; j + 4 <= je; j += 4) {
        int s0 = __builtin_amdgcn_readfirstlane(eidx[j]);
        int s1 = __builtin_amdgcn_readfirstlane(eidx[j + 1]);
        int s2 = __builtin_amdgcn_readfirstlane(eidx[j + 2]);
        int s3 = __builtin_amdgcn_readfirstlane(eidx[j + 3]);
        float w0 = wp[(size_t)j * 4 + hh];
        float w1 = wp[(size_t)(j + 1) * 4 + hh];
        float w2 = wp[(size_t)(j + 2) * 4 + hh];
        float w3 = wp[(size_t)(j + 3) * 4 + hh];
        unsigned int u0 = *(const unsigned int*)(xp16 + (size_t)s0 * 128 + 2 * lane);
        unsigned int u1 = *(const unsigned int*)(xp16 + (size_t)s1 * 128 + 2 * lane);
        unsigned int u2 = *(const unsigned int*)(xp16 + (size_t)s2 * 128 + 2 * lane);
        unsigned int u3 = *(const unsigned int*)(xp16 + (size_t)s3 * 128 + 2 * lane);
        a0 += w0 * b2f_lo(u0) + w1 * b2f_lo(u1) + w2 * b2f_lo(u2) + w3 * b2f_lo(u3);
        a1 += w0 * b2f_hi(u0) + w1 * b2f_hi(u1) + w2 * b2f_hi(u2) + w3 * b2f_hi(u3);
    }
    for (; j < je; ++j) {
        int s = __builtin_amdgcn_readfirstlane(eidx[j]);
        float w = wp[(size_t)j * 4 + hh];
        unsigned int u = *(const unsigned int*)(xp16 + (size_t)s * 128 + 2 * lane);
        a0 += w * b2f_lo(u);
        a1 += w * b2f_hi(u);
    }
    float inv = ((const float*)(invden + d))[hh];
    float2 o = make_float2(a0 * inv + bias[2 * lane], a1 * inv + bias[2 * lane + 1]);
    *(float2*)(out + (size_t)d * 128 + 2 * lane) = o;
}

// ---------------- accumulation, layer 2 ----------------
__global__ void k_accL2(const unsigned short* __restrict__ hb16, const float4* __restrict__ wp,
                        const float4* __restrict__ invden, const int* __restrict__ rowptr,
                        const int* __restrict__ eidx, unsigned short* __restrict__ agg16,
                        int N) {
    int d = (blockIdx.x * blockDim.x + threadIdx.x) >> 6;
    int lane = threadIdx.x & 63;
    if (d >= N) return;
    int jb = rowptr[d], je = rowptr[d + 1];
    float acc[4][2] = {{0.f, 0.f}, {0.f, 0.f}, {0.f, 0.f}, {0.f, 0.f}};
    int j = jb;
    for (; j + 4 <= je; j += 4) {
        int s0 = __builtin_amdgcn_readfirstlane(eidx[j]);
        int s1 = __builtin_amdgcn_readfirstlane(eidx[j + 1]);
        int s2 = __builtin_amdgcn_readfirstlane(eidx[j + 2]);
        int s3 = __builtin_amdgcn_readfirstlane(eidx[j + 3]);
        float4 w0 = wp[j], w1 = wp[j + 1], w2 = wp[j + 2], w3 = wp[j + 3];
        unsigned int u0 = *(const unsigned int*)(hb16 + (size_t)s0 * 128 + 2 * lane);
        unsigned int u1 = *(const unsigned int*)(hb16 + (size_t)s1 * 128 + 2 * lane);
        unsigned int u2 = *(const unsigned int*)(hb16 + (size_t)s2 * 128 + 2 * lane);
        unsigned int u3 = *(const unsigned int*)(hb16 + (size_t)s3 * 128 + 2 * lane);
        float lo0 = b2f_lo(u0), hi0 = b2f_hi(u0);
        float lo1 = b2f_lo(u1), hi1 = b2f_hi(u1);
        float lo2 = b2f_lo(u2), hi2 = b2f_hi(u2);
        float lo3 = b2f_lo(u3), hi3 = b2f_hi(u3);
#pragma unroll
        for (int hh = 0; hh < 4; hh++) {
            acc[hh][0] += ((const float*)&w0)[hh] * lo0 + ((const float*)&w1)[hh] * lo1 +
                          ((const float*)&w2)[hh] * lo2 + ((const float*)&w3)[hh] * lo3;
            acc[hh][1] += ((const float*)&w0)[hh] * hi0 + ((const float*)&w1)[hh] * hi1 +
                          ((const float*)&w2)[hh] * hi2 + ((const float*)&w3)[hh] * hi3;
        }
    }
    for (; j < je; ++j) {
        int s = __builtin_amdgcn_readfirstlane(eidx[j]);
        float4 w = wp[j];
        unsigned int u = *(const unsigned int*)(hb16 + (size_t)s * 128 + 2 * lane);
        float lo = b2f_lo(u), hi = b2f_hi(u);
#pragma unroll
        for (int hh = 0; hh < 4; hh++) {
            acc[hh][0] += ((const float*)&w)[hh] * lo;
            acc[hh][1] += ((const float*)&w)[hh] * hi;
        }
    }
    float4 inv = invden[d];
#pragma unroll
    for (int hh = 0; hh < 4; hh++) {
        float iv = ((const float*)&inv)[hh];
        ushort2 o = make_ushort2(f2b(acc[hh][0] * iv), f2b(acc[hh][1] * iv));
        *(ushort2*)(agg16 + (size_t)d * 512 + hh * 128 + 2 * lane) = o;
    }
}

// ---------------- batch norm ----------------
__global__ void k_bnstats(const float* __restrict__ x, float* __restrict__ sums, int N) {
    int col = threadIdx.x & 127, half = threadIdx.x >> 7;
    float s1 = 0.f, s2 = 0.f;
    for (int r = blockIdx.x * 2 + half; r < N; r += gridDim.x * 2) {
        float v = x[(size_t)r * 128 + col];
        s1 += v;
        s2 += v * v;
    }
    atomicAdd(&sums[col], s1);
    atomicAdd(&sums[128 + col], s2);
}

__global__ void k_bnapply(float* __restrict__ x, unsigned short* __restrict__ out16,
                          const float* __restrict__ sums, const float* __restrict__ gamma,
                          const float* __restrict__ beta, int N, int elu) {
    int idx = blockIdx.x * blockDim.x + threadIdx.x;
    if (idx >= N * 32) return;
    float4 v = ((float4*)x)[idx];
    int colb = (idx & 31) * 4;
    float invN = 1.f / (float)N;
#pragma unroll
    for (int j = 0; j < 4; j++) {
        int col = colb + j;
        float mu = sums[col] * invN;
        float var = sums[128 + col] * invN - mu * mu;
        float y = (((float*)&v)[j] - mu) * rsqrtf(var + EPS_BN) * gamma[col] + beta[col];
        if (elu) y = y > 0.f ? y : __expf(y) - 1.f;
        ((float*)&v)[j] = y;
    }
    ((float4*)x)[idx] = v;
    if (out16) {
        ushort4 o = make_ushort4(f2b(v.x), f2b(v.y), f2b(v.z), f2b(v.w));
        ((ushort4*)out16)[idx] = o;
    }
}

// ---------------- launch ----------------
extern "C" void kernel_launch(void* const* d_in, const int* in_sizes, int n_in,
                              void* d_out, int out_size, void* d_ws, size_t ws_size,
                              hipStream_t stream) {
    const float* x = (const float*)d_in[0];
    const int* ei_raw = (const int*)d_in[1];
    const float* W0 = (const float*)d_in[2];
    const float* as0 = (const float*)d_in[3];
    const float* ad0 = (const float*)d_in[4];
    const float* b0 = (const float*)d_in[5];
    const float* g0 = (const float*)d_in[6];
    const float* be0 = (const float*)d_in[7];
    const float* W1 = (const float*)d_in[8];
    const float* as1 = (const float*)d_in[9];
    const float* ad1 = (const float*)d_in[10];
    const float* b1 = (const float*)d_in[11];
    const float* g1 = (const float*)d_in[12];
    const float* be1 = (const float*)d_in[13];
    const float* W2 = (const float*)d_in[14];
    const float* as2 = (const float*)d_in[15];
    const float* ad2 = (const float*)d_in[16];
    const float* g2v = (const float*)d_in[18];
    const float* be2 = (const float*)d_in[19];

    const int N = in_sizes[0] / 128;
    const int E = in_sizes[1] / 2;

    // workspace carve (256B aligned)
    char* p = (char*)d_ws;
    auto alloc = [&](size_t bytes) {
        void* r = (void*)p;
        p += (bytes + 255) & ~(size_t)255;
        return r;
    };
    float* hbuf = (float*)alloc((size_t)N * 128 * 4);
    unsigned short* xb = (unsigned short*)alloc((size_t)N * 128 * 2);
    unsigned short* xp16 = (unsigned short*)alloc((size_t)N * 128 * 2);
    unsigned short* hb16 = (unsigned short*)alloc((size_t)N * 128 * 2);
    unsigned short* agg16 = (unsigned short*)alloc((size_t)N * 512 * 2);
    float* As = (float*)alloc((size_t)N * 4 * 4);
    float* Ad = (float*)alloc((size_t)N * 4 * 4);
    int* deg = (int*)alloc((size_t)N * 4);
    int* rowptr = (int*)alloc((size_t)(N + 1) * 4);
    int* bsum = (int*)alloc(1024);
    int* eidx = (int*)alloc((size_t)(E + N) * 4);
    float* bns = (float*)alloc(256 * 4);
    float4* wp = (float4*)alloc((size_t)(E + N) * 16);
    float4* invden = (float4*)alloc((size_t)N * 16);
    int* flag = (int*)alloc(256);
    float* Wt = (float*)alloc(1024 * 4);
    unsigned short* WT0 = (unsigned short*)alloc((size_t)128 * 128 * 2);
    unsigned short* WT1 = (unsigned short*)alloc((size_t)128 * 128 * 2);
    unsigned short* WT2 = (unsigned short*)alloc((size_t)128 * 512 * 2);
    int2* pairs = (int2*)alloc((size_t)NBUK * BCAP * 8);
    int* gcnt = (int*)alloc(NBUK * 4);
    if ((size_t)(p - (char*)d_ws) > ws_size) return;

    const int nb = (N + 255) / 256;
    const int gw = (N + 3) / 4;
    const int gt = (N + 63) / 64;
    const int nbuk_used = (N + (1 << BSHIFT) - 1) >> BSHIFT;

    // --- CSR build (bucketed, LDS-sorted) ---
    k_detect64<<<1, 64, 0, stream>>>(ei_raw, flag, 2 * E);
    hipMemsetAsync(gcnt, 0, NBUK * 4, stream);
    k_bin<<<(E + 1023) / 1024, 256, 0, stream>>>(ei_raw, flag, E, gcnt, pairs);
    k_bdeg2<<<nbuk_used, 256, 0, stream>>>(pairs, gcnt, deg, N);
    k_scan1<<<nb, 256, 0, stream>>>(deg, rowptr, bsum, N);
    k_scan2<<<1, 256, 0, stream>>>(bsum, nb);
    k_scan3<<<nb, 256, 0, stream>>>(rowptr, bsum, N);
    k_bsort<<<nbuk_used, 256, 0, stream>>>(pairs, gcnt, rowptr, eidx, N);

    // --- weight prep + input cast ---
    k_wcvt<<<(128 * 128 + 255) / 256, 256, 0, stream>>>(W0, WT0, 128, 128);
    k_wcvt<<<(128 * 128 + 255) / 256, 256, 0, stream>>>(W1, WT1, 128, 128);
    k_w2cvt<<<(128 * 512 + 255) / 256, 256, 0, stream>>>(W2, WT2);
    k_makeWt<<<256, 256, 0, stream>>>(W2, as2, ad2, Wt);
    k_f2b4<<<(N * 32 + 255) / 256, 256, 0, stream>>>(x, xb, N * 32);

    // --- layer 0 (GEMM fuses attention scores) ---
    k_tgemm<128><<<gt, 256, 0, stream>>>(xb, WT0, (float*)nullptr, xp16, as0, ad0, As, Ad, N);
    k_edgew<<<gw, 256, 0, stream>>>(As, Ad, rowptr, eidx, wp, invden, N);
    k_acc01<<<gw, 256, 0, stream>>>(xp16, (const float*)wp, invden, rowptr, eidx, b0, hbuf, N);
    hipMemsetAsync(bns, 0, 256 * 4, stream);
    k_bnstats<<<256, 256, 0, stream>>>(hbuf, bns, N);
    k_bnapply<<<(N * 32 + 255) / 256, 256, 0, stream>>>(hbuf, hb16, bns, g0, be0, N, 1);

    // --- layer 1 ---
    k_tgemm<128><<<gt, 256, 0, stream>>>(hb16, WT1, (float*)nullptr, xp16, as1, ad1, As, Ad, N);
    k_edgew<<<gw, 256, 0, stream>>>(As, Ad, rowptr, eidx, wp, invden, N);
    k_acc01<<<gw, 256, 0, stream>>>(xp16, (const float*)wp, invden, rowptr, eidx, b1, hbuf, N);
    hipMemsetAsync(bns, 0, 256 * 4, stream);
    k_bnstats<<<256, 256, 0, stream>>>(hbuf, bns, N);
    k_bnapply<<<(N * 32 + 255) / 256, 256, 0, stream>>>(hbuf, hb16, bns, g1, be1, N, 1);

    // --- layer 2 ---
    float* outf = (float*)d_out;
    k_attW<<<gw, 256, 0, stream>>>(hbuf, Wt, As, Ad, N);
    k_edgew<<<gw, 256, 0, stream>>>(As, Ad, rowptr, eidx, wp, invden, N);
    k_accL2<<<gw, 256, 0, stream>>>(hb16, wp, invden, rowptr, eidx, agg16, N);
    k_tgemm<512><<<gt, 256, 0, stream>>>(agg16, WT2, outf, (unsigned short*)nullptr,
                                         (const float*)nullptr, (const float*)nullptr,
                                         (float*)nullptr, (float*)nullptr, N);
    hipMemsetAsync(bns, 0, 256 * 4, stream);
    k_bnstats<<<256, 256, 0, stream>>>(outf, bns, N);
    k_bnapply<<<(N * 32 + 255) / 256, 256, 0, stream>>>(outf, (unsigned short*)nullptr, bns, g2v, be2, N, 0);
}